// Round 17
// baseline (164.869 us; speedup 1.0000x reference)
//
#include <hip/hip_runtime.h>

namespace {

typedef short    v4s __attribute__((ext_vector_type(4)));
typedef float    v4f __attribute__((ext_vector_type(4)));
typedef float    f4  __attribute__((ext_vector_type(4)));
typedef unsigned u2  __attribute__((ext_vector_type(2)));

constexpr int Tt = 512;
constexpr int Dd = 64;
constexpr int CH = 32;            // chunk length (steps)
constexpr float LN2 = 0.69314718055994530942f;

__device__ __forceinline__ unsigned pk_bf16(float a, float b) {
  unsigned ua = __float_as_uint(a), ub = __float_as_uint(b);
  ua += 0x7fffu + ((ua >> 16) & 1u);
  ub += 0x7fffu + ((ub >> 16) & 1u);
  return (ua >> 16) | (ub & 0xffff0000u);
}
__device__ __forceinline__ unsigned pktrunc(float lo, float hi) {
  return __builtin_amdgcn_perm(__float_as_uint(hi), __float_as_uint(lo), 0x07060302u);
}
__device__ __forceinline__ v4s mk4(unsigned lo, unsigned hi) {
  union { unsigned u[2]; v4s s; } z;
  z.u[0] = lo; z.u[1] = hi; return z.s;
}
__device__ __forceinline__ float bf_lo(unsigned u) { return __uint_as_float(u << 16); }
__device__ __forceinline__ float bf_hi(unsigned u) { return __uint_as_float(u & 0xffff0000u); }

__device__ __forceinline__ v4f mfma16(v4s a, v4s b, v4f c) {
  return __builtin_amdgcn_mfma_f32_16x16x16bf16_1k(a, b, c, 0, 0, 0);
}
__device__ __forceinline__ float fexp2(float x) {
#if __has_builtin(__builtin_amdgcn_exp2f)
  return __builtin_amdgcn_exp2f(x);
#else
  return exp2f(x);
#endif
}
__device__ __forceinline__ float rdlane(float v, int idx) {
  return __uint_as_float(__builtin_amdgcn_readlane(__float_as_uint(v), idx));
}

// E LDS index (u2 = 8B units) for (t_local in [0,32), x, wblk)
__device__ __forceinline__ int eidx(int tl, int x, int wblk) {
  return tl * 64 + x * 4 + (wblk ^ (x >> 2));
}

__global__ __launch_bounds__(128, 1) void fhmm_fwd(
    const float* __restrict__ seq,     // [B, T, D]
    const int*   __restrict__ lengths, // [B]
    const float* __restrict__ pw,      // [16,16]
    const float* __restrict__ px,      // [16,16]
    const float* __restrict__ py,      // [16,16,64]
    float*       __restrict__ out)     // [B]
{
  const int b   = blockIdx.x;
  const int tid = threadIdx.x;
  const int wv  = tid >> 6;            // 0 = consumer (scan), 1 = producer (GEMM)
  const int l   = tid & 63;
  const int g   = l >> 4;
  const int x   = l & 15;

  __shared__ u2    Elds[2][CH * 64];           // double-buffered E' (2 × 16 KB)
  __shared__ float Mbufs[2][32];               // per-chunk max shifts
  __shared__ __align__(16) float MxT[CH * 20]; // producer-private transpose pad
  // LDS total = 32768 + 256 + 2560 = 35584 -> 4 blocks/CU (8 waves/CU)

  const int len = lengths[b];
  const int nch = (len + CH - 1) >> 5;
  const float* yb = seq + (size_t)b * (Tt * Dd);

  if (wv == 1) {
    // ==================== PRODUCER WAVE ====================
    // dif B-frag table entirely in registers (producer-private, 128 VGPR):
    // difB[st][c]: lane(g,x) holds B[k=4g+i][n=x] = dif[st*16+x][16c+4g+i]
    v4s difB[16][4];
    float bfull[16];
#pragma unroll
    for (int st = 0; st < 16; ++st) {
      float pt = 0.f;
#pragma unroll
      for (int c = 0; c < 4; ++c) {
        f4 pv = *(const f4*)(py + (st * 16 + x) * 64 + c * 16 + g * 4);
        float q0 = __log2f(1.f - pv.x), q1 = __log2f(1.f - pv.y),
              q2 = __log2f(1.f - pv.z), q3 = __log2f(1.f - pv.w);
        pt += (q0 + q1) + (q2 + q3);
        difB[st][c] = mk4(pk_bf16(__log2f(pv.x) - q0, __log2f(pv.y) - q1),
                          pk_bf16(__log2f(pv.z) - q2, __log2f(pv.w) - q3));
      }
      pt += __shfl_xor(pt, 16, 64);
      pt += __shfl_xor(pt, 32, 64);
      bfull[st] = pt;   // base[st*16 + x]
    }

    const v4f z4 = {0.f, 0.f, 0.f, 0.f};
    f4 yv[8];           // next-chunk raw y (32 VGPR, double buffer)

#define YLOAD(TB)                                                             \
    _Pragma("unroll")                                                         \
    for (int m_ = 0; m_ < 2; ++m_)                                            \
      _Pragma("unroll")                                                       \
      for (int c_ = 0; c_ < 4; ++c_)                                          \
        yv[m_ * 4 + c_] = *(const f4*)(yb +                                   \
            (size_t)((TB) + m_ * 16 + x) * 64 + c_ * 16 + g * 4);

// pack current yv -> ya16, then immediately issue next chunk's loads
#define GEMMCHUNK(CHIDX)                                                      \
    {                                                                         \
      const int tb_  = (CHIDX) * CH; (void)tb_;                               \
      const int buf_ = (CHIDX) & 1;                                           \
      v4s ya16[2][4];                                                         \
      _Pragma("unroll")                                                       \
      for (int i_ = 0; i_ < 8; ++i_)                                          \
        ya16[i_ >> 2][i_ & 3] = mk4(pktrunc(yv[i_].x, yv[i_].y),              \
                                    pktrunc(yv[i_].z, yv[i_].w));             \
      if ((CHIDX) + 1 < nch) { YLOAD(((CHIDX) + 1) * CH) }                    \
      float mx_[2][4];                                                        \
      _Pragma("unroll")                                                       \
      for (int mt_ = 0; mt_ < 2; ++mt_)                                       \
        _Pragma("unroll")                                                     \
        for (int id_ = 0; id_ < 4; ++id_) mx_[mt_][id_] = -1e30f;             \
      _Pragma("unroll")                                                       \
      for (int q_ = 0; q_ < 4; ++q_) {                                        \
        const float b0_ = bfull[4 * q_ + 0], b1_ = bfull[4 * q_ + 1],         \
                    b2_ = bfull[4 * q_ + 2], b3_ = bfull[4 * q_ + 3];         \
        _Pragma("unroll")                                                     \
        for (int mt_ = 0; mt_ < 2; ++mt_) {                                   \
          v4f a0_ = z4, a1_ = z4, a2_ = z4, a3_ = z4;                         \
          _Pragma("unroll")                                                   \
          for (int c_ = 0; c_ < 4; ++c_) {                                    \
            a0_ = mfma16(ya16[mt_][c_], difB[4 * q_ + 0][c_], a0_);           \
            a1_ = mfma16(ya16[mt_][c_], difB[4 * q_ + 1][c_], a1_);           \
            a2_ = mfma16(ya16[mt_][c_], difB[4 * q_ + 2][c_], a2_);           \
            a3_ = mfma16(ya16[mt_][c_], difB[4 * q_ + 3][c_], a3_);           \
          }                                                                   \
          _Pragma("unroll")                                                   \
          for (int id_ = 0; id_ < 4; ++id_) {                                 \
            const float e0_ = a0_[id_] + b0_, e1_ = a1_[id_] + b1_,           \
                        e2_ = a2_[id_] + b2_, e3_ = a3_[id_] + b3_;           \
            u2 wv_;                                                           \
            wv_.x = pk_bf16(e0_, e1_);                                        \
            wv_.y = pk_bf16(e2_, e3_);                                        \
            Elds[buf_][eidx(mt_ * 16 + 4 * g + id_, x, q_)] = wv_;            \
            const float mq_ = fmaxf(fmaxf(e0_, e1_), fmaxf(e2_, e3_));        \
            mx_[mt_][id_] = fmaxf(mx_[mt_][id_], mq_);                        \
          }                                                                   \
        }                                                                     \
      }                                                                       \
      _Pragma("unroll")                                                       \
      for (int mt_ = 0; mt_ < 2; ++mt_)                                       \
        _Pragma("unroll")                                                     \
        for (int id_ = 0; id_ < 4; ++id_)                                     \
          MxT[(mt_ * 16 + 4 * g + id_) * 20 + x] = mx_[mt_][id_];             \
      {  /* same-wave LDS transpose read (no barrier needed) */               \
        const f4* row_ = (const f4*)&MxT[(l & 31) * 20];                      \
        f4 r0_ = row_[0], r1_ = row_[1], r2_ = row_[2], r3_ = row_[3];        \
        const float m01_ = fmaxf(fmaxf(r0_.x, r0_.y), fmaxf(r0_.z, r0_.w));  \
        const float m23_ = fmaxf(fmaxf(r1_.x, r1_.y), fmaxf(r1_.z, r1_.w));  \
        const float m45_ = fmaxf(fmaxf(r2_.x, r2_.y), fmaxf(r2_.z, r2_.w));  \
        const float m67_ = fmaxf(fmaxf(r3_.x, r3_.y), fmaxf(r3_.z, r3_.w));  \
        const float Mr_ = fmaxf(fmaxf(m01_, m23_), fmaxf(m45_, m67_));        \
        if (l < 32) Mbufs[buf_][l] = Mr_;                                     \
      }                                                                       \
    }

    YLOAD(0)
    GEMMCHUNK(0)
    __syncthreads();                       // buf0 ready
#pragma unroll 1
    for (int ch = 0; ch < nch; ++ch) {
      if (ch + 1 < nch) GEMMCHUNK(ch + 1)  // overlaps consumer's scan(ch)
      __syncthreads();                     // GEMM(ch+1) done & scan(ch) done
    }
#undef GEMMCHUNK
#undef YLOAD

  } else {
    // ==================== CONSUMER WAVE ====================
    v4s pwB, pxB;
    {
      const int r0 = (4 * g) * 16 + x;
      pwB = mk4(pk_bf16(pw[r0], pw[r0 + 16]), pk_bf16(pw[r0 + 32], pw[r0 + 48]));
      pxB = mk4(pk_bf16(px[r0], px[r0 + 16]), pk_bf16(px[r0 + 32], px[r0 + 48]));
    }
    const float p0w0 = pw[4 * g + 0], p0w1 = pw[4 * g + 1],
                p0w2 = pw[4 * g + 2], p0w3 = pw[4 * g + 3];
    const float px0 = px[x];

    float acc  = 0.f;
    float msum = 0.f;
    v4f al = {0.f, 0.f, 0.f, 0.f};
    const v4f z4 = {0.f, 0.f, 0.f, 0.f};

    __syncthreads();                       // wait buf0
#pragma unroll 1
    for (int ch = 0; ch < nch; ++ch) {
      const int tb  = ch * CH;
      const int buf = ch & 1;
      const int te  = (len < tb + CH) ? len : (tb + CH);
      const u2* Eb  = Elds[buf];

      float Mrow = Mbufs[buf][l & 31];     // lane l<32 holds M[tb+l]
      if (l < 32 && tb + l < len) msum += Mrow;

      int t = tb;
      u2 Ec = Eb[eidx(0, x, g)];

#define SCAN_STEP(TCUR, PF)                                                 \
      {                                                                     \
        u2 En_ = Ec;                                                        \
        PF                                                                  \
        const float Ms_ = rdlane(Mrow, (TCUR) & 31);                        \
        const float e0 = fexp2(bf_lo(Ec.x) - Ms_);                          \
        const float e1 = fexp2(bf_hi(Ec.x) - Ms_);                          \
        const float e2 = fexp2(bf_lo(Ec.y) - Ms_);                          \
        const float e3 = fexp2(bf_hi(Ec.y) - Ms_);                          \
        v4s a16 = mk4(pktrunc(al[0], al[1]), pktrunc(al[2], al[3]));        \
        v4f d1 = mfma16(a16, pwB, z4);                                      \
        v4s d16 = mk4(pktrunc(d1[0], d1[1]), pktrunc(d1[2], d1[3]));        \
        v4f d2 = mfma16(d16, pxB, z4);                                      \
        al[0] = d2[0] * e0; al[1] = d2[1] * e1;                             \
        al[2] = d2[2] * e2; al[3] = d2[3] * e3;                             \
        Ec = En_;                                                           \
      }

#define RENORM                                                              \
      {                                                                     \
        float S = (al[0] + al[1]) + (al[2] + al[3]);                        \
        _Pragma("unroll")                                                   \
        for (int o = 1; o <= 32; o <<= 1) S += __shfl_xor(S, o, 64);        \
        S = fmaxf(S, 1e-35f);                                               \
        const float r = __builtin_amdgcn_rcpf(S);                           \
        al[0] *= r; al[1] *= r; al[2] *= r; al[3] *= r;                     \
        acc += __log2f(S);                                                  \
      }

      if (ch == 0) {   // peel t = 0: alpha0 = prior * e
        const float Ms_ = rdlane(Mrow, 0);
        const float e0 = fexp2(bf_lo(Ec.x) - Ms_);
        const float e1 = fexp2(bf_hi(Ec.x) - Ms_);
        const float e2 = fexp2(bf_lo(Ec.y) - Ms_);
        const float e3 = fexp2(bf_hi(Ec.y) - Ms_);
        al[0] = p0w0 * px0 * e0; al[1] = p0w1 * px0 * e1;
        al[2] = p0w2 * px0 * e2; al[3] = p0w3 * px0 * e3;
        t = 1;
        if (t < te) Ec = Eb[eidx(1, x, g)];
      }

      while (t < te && (t & 7)) {     // guarded entry until 8-aligned
        SCAN_STEP(t,
          if (t + 1 < te) { En_ = Eb[eidx((t + 1) & 31, x, g)]; })
        if ((t & 7) == 7) RENORM
        ++t;
      }

      const int ng = (te - t) >> 3;   // fast path: 8-step groups
      if (ng > 0) {
        u2 E1 = Eb[eidx((t + 1) & 31, x, g)];
        float snap = 0.f, Sready = 1.0f, rdy = 1.0f;
#pragma unroll 1
        for (int gi = 0; gi < ng; ++gi) {
#pragma unroll
          for (int k = 0; k < 8; ++k) {
            u2 E2 = Eb[eidx((t + k + 2) & 31, x, g)];   // 2-deep prefetch
            const float Ms_ = rdlane(Mrow, (t + k) & 31);
            float e0 = fexp2(bf_lo(Ec.x) - Ms_);
            float e1 = fexp2(bf_hi(Ec.x) - Ms_);
            float e2 = fexp2(bf_lo(Ec.y) - Ms_);
            float e3 = fexp2(bf_hi(Ec.y) - Ms_);
            if (k == 0) {       // apply previous group's renorm (off chain)
              e0 *= rdy; e1 *= rdy; e2 *= rdy; e3 *= rdy;
              acc += __log2f(Sready);
            }
            v4s a16 = mk4(pktrunc(al[0], al[1]), pktrunc(al[2], al[3]));
            v4f d1 = mfma16(a16, pwB, z4);
            v4s d16 = mk4(pktrunc(d1[0], d1[1]), pktrunc(d1[2], d1[3]));
            v4f d2 = mfma16(d16, pxB, z4);
            al[0] = d2[0] * e0; al[1] = d2[1] * e1;
            al[2] = d2[2] * e2; al[3] = d2[3] * e3;
            if (k == 0) snap = (al[0] + al[1]) + (al[2] + al[3]);
            if (k >= 1 && k <= 6)
              snap += __shfl_xor(snap, 1 << (k - 1), 64);
            if (k == 7) {
              Sready = fmaxf(snap, 1e-35f);
              rdy = __builtin_amdgcn_rcpf(Sready);
            }
            Ec = E1; E1 = E2;
          }
          t += 8;
        }
        acc += __log2f(Sready);     // flush pending renorm
        al[0] *= rdy; al[1] *= rdy; al[2] *= rdy; al[3] *= rdy;
      }

      while (t < te) {                // guarded tail
        SCAN_STEP(t,
          if (t + 1 < te) { En_ = Eb[eidx((t + 1) & 31, x, g)]; })
        if ((t & 7) == 7) RENORM
        ++t;
      }
#undef SCAN_STEP
#undef RENORM

      __syncthreads();   // scan(ch) done; producer's GEMM(ch+1) done
    }

    // ---------- finalize ----------
    float S = (al[0] + al[1]) + (al[2] + al[3]);
#pragma unroll
    for (int o = 1; o <= 32; o <<= 1) S += __shfl_xor(S, o, 64);
    S = fmaxf(S, 1e-35f);
    acc += __log2f(S);

#pragma unroll
    for (int o = 1; o <= 32; o <<= 1) msum += __shfl_xor(msum, o, 64);

    if (l == 0) out[b] = LN2 * (acc + msum);
  }
}

} // namespace

extern "C" void kernel_launch(void* const* d_in, const int* in_sizes, int n_in,
                              void* d_out, int out_size, void* d_ws, size_t ws_size,
                              hipStream_t stream) {
  const float* seq     = (const float*)d_in[0];
  const int*   lengths = (const int*)d_in[1];
  const float* pw      = (const float*)d_in[2];
  const float* px      = (const float*)d_in[3];
  const float* py      = (const float*)d_in[4];
  float*       out     = (float*)d_out;

  hipLaunchKernelGGL(fhmm_fwd, dim3(1024), dim3(128), 0, stream,
                     seq, lengths, pw, px, py, out);
}

// Round 18
// 125.010 us; speedup vs baseline: 1.3188x; 1.3188x over previous
//
#include <hip/hip_runtime.h>

namespace {

typedef short    v4s __attribute__((ext_vector_type(4)));
typedef float    v4f __attribute__((ext_vector_type(4)));
typedef float    f4  __attribute__((ext_vector_type(4)));
typedef unsigned u2  __attribute__((ext_vector_type(2)));

constexpr int Tt = 512;
constexpr int Dd = 64;
constexpr int CH = 32;            // chunk length (steps)
constexpr float LN2 = 0.69314718055994530942f;

__device__ __forceinline__ unsigned pk_bf16(float a, float b) {
  unsigned ua = __float_as_uint(a), ub = __float_as_uint(b);
  ua += 0x7fffu + ((ua >> 16) & 1u);
  ub += 0x7fffu + ((ub >> 16) & 1u);
  return (ua >> 16) | (ub & 0xffff0000u);
}
__device__ __forceinline__ unsigned pktrunc(float lo, float hi) {
  return __builtin_amdgcn_perm(__float_as_uint(hi), __float_as_uint(lo), 0x07060302u);
}
__device__ __forceinline__ v4s mk4(unsigned lo, unsigned hi) {
  union { unsigned u[2]; v4s s; } z;
  z.u[0] = lo; z.u[1] = hi; return z.s;
}
__device__ __forceinline__ float bf_lo(unsigned u) { return __uint_as_float(u << 16); }
__device__ __forceinline__ float bf_hi(unsigned u) { return __uint_as_float(u & 0xffff0000u); }

__device__ __forceinline__ v4f mfma16(v4s a, v4s b, v4f c) {
  return __builtin_amdgcn_mfma_f32_16x16x16bf16_1k(a, b, c, 0, 0, 0);
}
__device__ __forceinline__ float fexp2(float x) {
#if __has_builtin(__builtin_amdgcn_exp2f)
  return __builtin_amdgcn_exp2f(x);
#else
  return exp2f(x);
#endif
}
__device__ __forceinline__ float rdlane(float v, int idx) {
  return __uint_as_float(__builtin_amdgcn_readlane(__float_as_uint(v), idx));
}

// E LDS index (u2 = 8B units) for (t_local in [0,32), x, wblk)
__device__ __forceinline__ int eidx(int tl, int x, int wblk) {
  return tl * 64 + x * 4 + (wblk ^ (x >> 2));
}

__global__ __launch_bounds__(128, 1) void fhmm_fwd(
    const float* __restrict__ seq,     // [B, T, D]
    const int*   __restrict__ lengths, // [B]
    const float* __restrict__ pw,      // [16,16]
    const float* __restrict__ px,      // [16,16]
    const float* __restrict__ py,      // [16,16,64]
    float*       __restrict__ out,     // [B]
    u2*          __restrict__ wsdif)   // [16*4*64] B-frag table (shared, 32 KB)
{
  const int b   = blockIdx.x;
  const int tid = threadIdx.x;
  const int wv  = tid >> 6;            // 0 = consumer (scan), 1 = producer (GEMM)
  const int l   = tid & 63;
  const int g   = l >> 4;
  const int x   = l & 15;

  __shared__ u2    Elds[2][CH * 64];           // double-buffered E' (2 × 16 KB)
  __shared__ float Mbufs[2][32];               // per-chunk max shifts
  __shared__ __align__(16) float MxT[CH * 20]; // producer-private transpose pad
  // LDS total = 32768 + 256 + 2560 = 35584 -> 4 blocks/CU (8 waves/CU)

  const int len = lengths[b];
  const int nch = (len + CH - 1) >> 5;
  const float* yb = seq + (size_t)b * (Tt * Dd);

  if (wv == 1) {
    // ==================== PRODUCER WAVE ====================
    // Half the dif table register-resident (states 0..7 = q-tiles 0,1: 64 VGPR);
    // states 8..15 streamed from wsdif per chunk with early issue.
    v4s Bp[32];          // Bp[q*16 + j*4 + c], q in {0,1}
    float bfull[16];
#pragma unroll
    for (int st = 0; st < 16; ++st) {
      float pt = 0.f;
#pragma unroll
      for (int c = 0; c < 4; ++c) {
        f4 pv = *(const f4*)(py + (st * 16 + x) * 64 + c * 16 + g * 4);
        float q0 = __log2f(1.f - pv.x), q1 = __log2f(1.f - pv.y),
              q2 = __log2f(1.f - pv.z), q3 = __log2f(1.f - pv.w);
        pt += (q0 + q1) + (q2 + q3);
        v4s frag = mk4(pk_bf16(__log2f(pv.x) - q0, __log2f(pv.y) - q1),
                       pk_bf16(__log2f(pv.z) - q2, __log2f(pv.w) - q3));
        if (st < 8) Bp[st * 4 + c] = frag;
        union { v4s s; u2 u; } zz; zz.s = frag;
        wsdif[(st * 4 + c) * 64 + l] = zz.u;   // all blocks: identical bytes
      }
      pt += __shfl_xor(pt, 16, 64);
      pt += __shfl_xor(pt, 32, 64);
      bfull[st] = pt;   // base[st*16 + x]
    }

    const v4f z4 = {0.f, 0.f, 0.f, 0.f};
    f4 yv[8];           // next-chunk raw y (32 VGPR, double buffer)

#define YLOAD(TB)                                                             \
    _Pragma("unroll")                                                         \
    for (int m_ = 0; m_ < 2; ++m_)                                            \
      _Pragma("unroll")                                                       \
      for (int c_ = 0; c_ < 4; ++c_)                                          \
        yv[m_ * 4 + c_] = *(const f4*)(yb +                                   \
            (size_t)((TB) + m_ * 16 + x) * 64 + c_ * 16 + g * 4);

#define BQLOAD(DST, QN)                                                       \
    _Pragma("unroll")                                                         \
    for (int j_ = 0; j_ < 4; ++j_)                                            \
      _Pragma("unroll")                                                       \
      for (int c_ = 0; c_ < 4; ++c_) {                                        \
        u2 w_ = wsdif[(((QN) * 4 + j_) * 4 + c_) * 64 + l];                   \
        DST[j_ * 4 + c_] = mk4(w_.x, w_.y);                                   \
      }

#define GEMM_ONE(ARR, QI)                                                     \
    {                                                                         \
      const float b0_ = bfull[4 * (QI) + 0], b1_ = bfull[4 * (QI) + 1],       \
                  b2_ = bfull[4 * (QI) + 2], b3_ = bfull[4 * (QI) + 3];       \
      _Pragma("unroll")                                                       \
      for (int mt_ = 0; mt_ < 2; ++mt_) {                                     \
        v4f a0_ = z4, a1_ = z4, a2_ = z4, a3_ = z4;                           \
        _Pragma("unroll")                                                     \
        for (int c_ = 0; c_ < 4; ++c_) {                                      \
          a0_ = mfma16(ya16[mt_][c_], ARR[c_],      a0_);                     \
          a1_ = mfma16(ya16[mt_][c_], ARR[4 + c_],  a1_);                     \
          a2_ = mfma16(ya16[mt_][c_], ARR[8 + c_],  a2_);                     \
          a3_ = mfma16(ya16[mt_][c_], ARR[12 + c_], a3_);                     \
        }                                                                     \
        _Pragma("unroll")                                                     \
        for (int id_ = 0; id_ < 4; ++id_) {                                   \
          const float e0_ = a0_[id_] + b0_, e1_ = a1_[id_] + b1_,             \
                      e2_ = a2_[id_] + b2_, e3_ = a3_[id_] + b3_;             \
          u2 wv_;                                                             \
          wv_.x = pk_bf16(e0_, e1_);                                          \
          wv_.y = pk_bf16(e2_, e3_);                                          \
          Elds[buf_][eidx(mt_ * 16 + 4 * g + id_, x, (QI))] = wv_;            \
          const float mq_ = fmaxf(fmaxf(e0_, e1_), fmaxf(e2_, e3_));          \
          mx_[mt_][id_] = fmaxf(mx_[mt_][id_], mq_);                          \
        }                                                                     \
      }                                                                       \
    }

#define GEMMCHUNK(CHIDX)                                                      \
    {                                                                         \
      const int buf_ = (CHIDX) & 1;                                           \
      v4s B2[16], B3[16];                                                     \
      BQLOAD(B2, 2)            /* issue early: covered by q0/q1 MFMAs */      \
      BQLOAD(B3, 3)                                                           \
      v4s ya16[2][4];                                                         \
      _Pragma("unroll")                                                       \
      for (int i_ = 0; i_ < 8; ++i_)                                          \
        ya16[i_ >> 2][i_ & 3] = mk4(pktrunc(yv[i_].x, yv[i_].y),              \
                                    pktrunc(yv[i_].z, yv[i_].w));             \
      if ((CHIDX) + 1 < nch) { YLOAD(((CHIDX) + 1) * CH) }                    \
      float mx_[2][4];                                                        \
      _Pragma("unroll")                                                       \
      for (int mt_ = 0; mt_ < 2; ++mt_)                                       \
        _Pragma("unroll")                                                     \
        for (int id_ = 0; id_ < 4; ++id_) mx_[mt_][id_] = -1e30f;             \
      GEMM_ONE(Bp, 0)                                                         \
      GEMM_ONE((Bp + 16), 1)                                                  \
      GEMM_ONE(B2, 2)                                                         \
      GEMM_ONE(B3, 3)                                                         \
      _Pragma("unroll")                                                       \
      for (int mt_ = 0; mt_ < 2; ++mt_)                                       \
        _Pragma("unroll")                                                     \
        for (int id_ = 0; id_ < 4; ++id_)                                     \
          MxT[(mt_ * 16 + 4 * g + id_) * 20 + x] = mx_[mt_][id_];             \
      {  /* same-wave LDS transpose read (no barrier needed) */               \
        const f4* row_ = (const f4*)&MxT[(l & 31) * 20];                      \
        f4 r0_ = row_[0], r1_ = row_[1], r2_ = row_[2], r3_ = row_[3];        \
        const float m01_ = fmaxf(fmaxf(r0_.x, r0_.y), fmaxf(r0_.z, r0_.w));  \
        const float m23_ = fmaxf(fmaxf(r1_.x, r1_.y), fmaxf(r1_.z, r1_.w));  \
        const float m45_ = fmaxf(fmaxf(r2_.x, r2_.y), fmaxf(r2_.z, r2_.w));  \
        const float m67_ = fmaxf(fmaxf(r3_.x, r3_.y), fmaxf(r3_.z, r3_.w));  \
        const float Mr_ = fmaxf(fmaxf(m01_, m23_), fmaxf(m45_, m67_));        \
        if (l < 32) Mbufs[buf_][l] = Mr_;                                     \
      }                                                                       \
    }

    YLOAD(0)
    GEMMCHUNK(0)
    __syncthreads();                       // buf0 ready
#pragma unroll 1
    for (int ch = 0; ch < nch; ++ch) {
      if (ch + 1 < nch) GEMMCHUNK(ch + 1)  // overlaps consumer's scan(ch)
      __syncthreads();                     // GEMM(ch+1) done & scan(ch) done
    }
#undef GEMMCHUNK
#undef GEMM_ONE
#undef BQLOAD
#undef YLOAD

  } else {
    // ==================== CONSUMER WAVE ====================
    v4s pwB, pxB;
    {
      const int r0 = (4 * g) * 16 + x;
      pwB = mk4(pk_bf16(pw[r0], pw[r0 + 16]), pk_bf16(pw[r0 + 32], pw[r0 + 48]));
      pxB = mk4(pk_bf16(px[r0], px[r0 + 16]), pk_bf16(px[r0 + 32], px[r0 + 48]));
    }
    const float p0w0 = pw[4 * g + 0], p0w1 = pw[4 * g + 1],
                p0w2 = pw[4 * g + 2], p0w3 = pw[4 * g + 3];
    const float px0 = px[x];

    float acc  = 0.f;
    float msum = 0.f;
    v4f al = {0.f, 0.f, 0.f, 0.f};
    const v4f z4 = {0.f, 0.f, 0.f, 0.f};

    __syncthreads();                       // wait buf0
#pragma unroll 1
    for (int ch = 0; ch < nch; ++ch) {
      const int tb  = ch * CH;
      const int buf = ch & 1;
      const int te  = (len < tb + CH) ? len : (tb + CH);
      const u2* Eb  = Elds[buf];

      float Mrow = Mbufs[buf][l & 31];     // lane l<32 holds M[tb+l]
      if (l < 32 && tb + l < len) msum += Mrow;

      int t = tb;
      u2 Ec = Eb[eidx(0, x, g)];

#define SCAN_STEP(TCUR, PF)                                                 \
      {                                                                     \
        u2 En_ = Ec;                                                        \
        PF                                                                  \
        const float Ms_ = rdlane(Mrow, (TCUR) & 31);                        \
        const float e0 = fexp2(bf_lo(Ec.x) - Ms_);                          \
        const float e1 = fexp2(bf_hi(Ec.x) - Ms_);                          \
        const float e2 = fexp2(bf_lo(Ec.y) - Ms_);                          \
        const float e3 = fexp2(bf_hi(Ec.y) - Ms_);                          \
        v4s a16 = mk4(pktrunc(al[0], al[1]), pktrunc(al[2], al[3]));        \
        v4f d1 = mfma16(a16, pwB, z4);                                      \
        v4s d16 = mk4(pktrunc(d1[0], d1[1]), pktrunc(d1[2], d1[3]));        \
        v4f d2 = mfma16(d16, pxB, z4);                                      \
        al[0] = d2[0] * e0; al[1] = d2[1] * e1;                             \
        al[2] = d2[2] * e2; al[3] = d2[3] * e3;                             \
        Ec = En_;                                                           \
      }

#define RENORM                                                              \
      {                                                                     \
        float S = (al[0] + al[1]) + (al[2] + al[3]);                        \
        _Pragma("unroll")                                                   \
        for (int o = 1; o <= 32; o <<= 1) S += __shfl_xor(S, o, 64);        \
        S = fmaxf(S, 1e-35f);                                               \
        const float r = __builtin_amdgcn_rcpf(S);                           \
        al[0] *= r; al[1] *= r; al[2] *= r; al[3] *= r;                     \
        acc += __log2f(S);                                                  \
      }

      if (ch == 0) {   // peel t = 0: alpha0 = prior * e
        const float Ms_ = rdlane(Mrow, 0);
        const float e0 = fexp2(bf_lo(Ec.x) - Ms_);
        const float e1 = fexp2(bf_hi(Ec.x) - Ms_);
        const float e2 = fexp2(bf_lo(Ec.y) - Ms_);
        const float e3 = fexp2(bf_hi(Ec.y) - Ms_);
        al[0] = p0w0 * px0 * e0; al[1] = p0w1 * px0 * e1;
        al[2] = p0w2 * px0 * e2; al[3] = p0w3 * px0 * e3;
        t = 1;
        if (t < te) Ec = Eb[eidx(1, x, g)];
      }

      while (t < te && (t & 7)) {     // guarded entry until 8-aligned
        SCAN_STEP(t,
          if (t + 1 < te) { En_ = Eb[eidx((t + 1) & 31, x, g)]; })
        if ((t & 7) == 7) RENORM
        ++t;
      }

      const int ng = (te - t) >> 3;   // fast path: 8-step groups
      if (ng > 0) {
        u2 E1 = Eb[eidx((t + 1) & 31, x, g)];
        float snap = 0.f, Sready = 1.0f, rdy = 1.0f;
#pragma unroll 1
        for (int gi = 0; gi < ng; ++gi) {
#pragma unroll
          for (int k = 0; k < 8; ++k) {
            u2 E2 = Eb[eidx((t + k + 2) & 31, x, g)];   // 2-deep prefetch
            const float Ms_ = rdlane(Mrow, (t + k) & 31);
            float e0 = fexp2(bf_lo(Ec.x) - Ms_);
            float e1 = fexp2(bf_hi(Ec.x) - Ms_);
            float e2 = fexp2(bf_lo(Ec.y) - Ms_);
            float e3 = fexp2(bf_hi(Ec.y) - Ms_);
            if (k == 0) {       // apply previous group's renorm (off chain)
              e0 *= rdy; e1 *= rdy; e2 *= rdy; e3 *= rdy;
              acc += __log2f(Sready);
            }
            v4s a16 = mk4(pktrunc(al[0], al[1]), pktrunc(al[2], al[3]));
            v4f d1 = mfma16(a16, pwB, z4);
            v4s d16 = mk4(pktrunc(d1[0], d1[1]), pktrunc(d1[2], d1[3]));
            v4f d2 = mfma16(d16, pxB, z4);
            al[0] = d2[0] * e0; al[1] = d2[1] * e1;
            al[2] = d2[2] * e2; al[3] = d2[3] * e3;
            if (k == 0) snap = (al[0] + al[1]) + (al[2] + al[3]);
            if (k >= 1 && k <= 6)
              snap += __shfl_xor(snap, 1 << (k - 1), 64);
            if (k == 7) {
              Sready = fmaxf(snap, 1e-35f);
              rdy = __builtin_amdgcn_rcpf(Sready);
            }
            Ec = E1; E1 = E2;
          }
          t += 8;
        }
        acc += __log2f(Sready);     // flush pending renorm
        al[0] *= rdy; al[1] *= rdy; al[2] *= rdy; al[3] *= rdy;
      }

      while (t < te) {                // guarded tail
        SCAN_STEP(t,
          if (t + 1 < te) { En_ = Eb[eidx((t + 1) & 31, x, g)]; })
        if ((t & 7) == 7) RENORM
        ++t;
      }
#undef SCAN_STEP
#undef RENORM

      __syncthreads();   // scan(ch) done; producer's GEMM(ch+1) done
    }

    // ---------- finalize ----------
    float S = (al[0] + al[1]) + (al[2] + al[3]);
#pragma unroll
    for (int o = 1; o <= 32; o <<= 1) S += __shfl_xor(S, o, 64);
    S = fmaxf(S, 1e-35f);
    acc += __log2f(S);

#pragma unroll
    for (int o = 1; o <= 32; o <<= 1) msum += __shfl_xor(msum, o, 64);

    if (l == 0) out[b] = LN2 * (acc + msum);
  }
}

} // namespace

extern "C" void kernel_launch(void* const* d_in, const int* in_sizes, int n_in,
                              void* d_out, int out_size, void* d_ws, size_t ws_size,
                              hipStream_t stream) {
  const float* seq     = (const float*)d_in[0];
  const int*   lengths = (const int*)d_in[1];
  const float* pw      = (const float*)d_in[2];
  const float* px      = (const float*)d_in[3];
  const float* py      = (const float*)d_in[4];
  float*       out     = (float*)d_out;
  u2*          wsdif   = (u2*)d_ws;    // 32 KB shared B-frag table

  hipLaunchKernelGGL(fhmm_fwd, dim3(1024), dim3(128), 0, stream,
                     seq, lengths, pw, px, py, out, wsdif);
}

// Round 19
// 96.993 us; speedup vs baseline: 1.6998x; 1.2888x over previous
//
#include <hip/hip_runtime.h>

namespace {

typedef short    v4s __attribute__((ext_vector_type(4)));
typedef float    v4f __attribute__((ext_vector_type(4)));
typedef float    f4  __attribute__((ext_vector_type(4)));
typedef unsigned u2  __attribute__((ext_vector_type(2)));

constexpr int Tt = 512;
constexpr int Dd = 64;
constexpr int CH = 32;            // chunk length (steps)
constexpr float LN2 = 0.69314718055994530942f;

__device__ __forceinline__ unsigned pk_bf16(float a, float b) {
  unsigned ua = __float_as_uint(a), ub = __float_as_uint(b);
  ua += 0x7fffu + ((ua >> 16) & 1u);
  ub += 0x7fffu + ((ub >> 16) & 1u);
  return (ua >> 16) | (ub & 0xffff0000u);
}
__device__ __forceinline__ unsigned pktrunc(float lo, float hi) {
  return __builtin_amdgcn_perm(__float_as_uint(hi), __float_as_uint(lo), 0x07060302u);
}
__device__ __forceinline__ v4s mk4(unsigned lo, unsigned hi) {
  union { unsigned u[2]; v4s s; } z;
  z.u[0] = lo; z.u[1] = hi; return z.s;
}
__device__ __forceinline__ float bf_lo(unsigned u) { return __uint_as_float(u << 16); }
__device__ __forceinline__ float bf_hi(unsigned u) { return __uint_as_float(u & 0xffff0000u); }

__device__ __forceinline__ v4f mfma16(v4s a, v4s b, v4f c) {
  return __builtin_amdgcn_mfma_f32_16x16x16bf16_1k(a, b, c, 0, 0, 0);
}
__device__ __forceinline__ float fexp2(float x) {
#if __has_builtin(__builtin_amdgcn_exp2f)
  return __builtin_amdgcn_exp2f(x);
#else
  return exp2f(x);
#endif
}
__device__ __forceinline__ float rdlane(float v, int idx) {
  return __uint_as_float(__builtin_amdgcn_readlane(__float_as_uint(v), idx));
}

// E LDS index (u2 = 8B units) for (t_local in [0,32), x, wblk)
__device__ __forceinline__ int eidx(int tl, int x, int wblk) {
  return tl * 64 + x * 4 + (wblk ^ (x >> 2));
}

__global__ __launch_bounds__(192, 3) void fhmm_fwd(
    const float* __restrict__ seq,     // [B, T, D]
    const int*   __restrict__ lengths, // [B]
    const float* __restrict__ pw,      // [16,16]
    const float* __restrict__ px,      // [16,16]
    const float* __restrict__ py,      // [16,16,64]
    float*       __restrict__ out,     // [B]
    u2*          __restrict__ wsdif)   // [16*4*64] B-frag table (shared, 32 KB)
{
  const int b   = blockIdx.x;
  const int tid = threadIdx.x;
  const int wv  = tid >> 6;   // 0 = consumer; 1 = producer-A (q0,1); 2 = producer-B (q2,3)
  const int l   = tid & 63;
  const int g   = l >> 4;
  const int x   = l & 15;

  __shared__ u2    Elds[2][CH * 64];            // double-buffered E' (2 × 16 KB)
  __shared__ float Mpart[2][2][32];             // per-chunk, per-producer max
  __shared__ __align__(16) float MxTa[CH * 20]; // producer-A private pad
  __shared__ __align__(16) float MxTb[CH * 20]; // producer-B private pad
  // LDS = 32768 + 512 + 2*2560 = 38400 -> 4 blocks/CU (12 waves/CU)

  const int len = lengths[b];
  const int nch = (len + CH - 1) >> 5;
  const float* yb = seq + (size_t)b * (Tt * Dd);

  if (wv >= 1) {
    // ==================== PRODUCER WAVE (A: q0,1 | B: q2,3) ====================
    const int qb = (wv - 1) * 2;                 // first q-tile owned
    float* MxT = (wv == 1) ? MxTa : MxTb;

    float bfull[8];                              // bases for OUR 8 states only
#pragma unroll
    for (int s8 = 0; s8 < 8; ++s8) {
      const int st = qb * 4 + s8;
      float pt = 0.f;
#pragma unroll
      for (int c = 0; c < 4; ++c) {
        f4 pv = *(const f4*)(py + (st * 16 + x) * 64 + c * 16 + g * 4);
        float q0 = __log2f(1.f - pv.x), q1 = __log2f(1.f - pv.y),
              q2 = __log2f(1.f - pv.z), q3 = __log2f(1.f - pv.w);
        pt += (q0 + q1) + (q2 + q3);
        u2 wvv;
        wvv.x = pk_bf16(__log2f(pv.x) - q0, __log2f(pv.y) - q1);
        wvv.y = pk_bf16(__log2f(pv.z) - q2, __log2f(pv.w) - q3);
        wsdif[(st * 4 + c) * 64 + l] = wvv;      // all blocks: identical bytes
      }
      pt += __shfl_xor(pt, 16, 64);
      pt += __shfl_xor(pt, 32, 64);
      bfull[s8] = pt;                            // base[st*16 + x]
    }

    const v4f z4 = {0.f, 0.f, 0.f, 0.f};
    f4 yv[8];                                    // next-chunk raw y (32 VGPR)

#define YLOAD(TB)                                                             \
    _Pragma("unroll")                                                         \
    for (int m_ = 0; m_ < 2; ++m_)                                            \
      _Pragma("unroll")                                                       \
      for (int c_ = 0; c_ < 4; ++c_)                                          \
        yv[m_ * 4 + c_] = *(const f4*)(yb +                                   \
            (size_t)((TB) + m_ * 16 + x) * 64 + c_ * 16 + g * 4);

#define GEMMCHUNK(CHIDX)                                                      \
    {                                                                         \
      const int buf_ = (CHIDX) & 1;                                           \
      v4s ya16[2][4];                                                         \
      _Pragma("unroll")                                                       \
      for (int i_ = 0; i_ < 8; ++i_)                                          \
        ya16[i_ >> 2][i_ & 3] = mk4(pktrunc(yv[i_].x, yv[i_].y),              \
                                    pktrunc(yv[i_].z, yv[i_].w));             \
      if ((CHIDX) + 1 < nch) { YLOAD(((CHIDX) + 1) * CH) }                    \
      float mx_[2][4];                                                        \
      _Pragma("unroll")                                                       \
      for (int mt_ = 0; mt_ < 2; ++mt_)                                       \
        _Pragma("unroll")                                                     \
        for (int id_ = 0; id_ < 4; ++id_) mx_[mt_][id_] = -1e30f;             \
      _Pragma("unroll")                                                       \
      for (int q2_ = 0; q2_ < 2; ++q2_) {                                     \
        const int q_ = qb + q2_;                                              \
        v4s Bq[16];                                                           \
        _Pragma("unroll")                                                     \
        for (int j_ = 0; j_ < 4; ++j_)                                        \
          _Pragma("unroll")                                                   \
          for (int c_ = 0; c_ < 4; ++c_) {                                    \
            u2 w_ = wsdif[((q_ * 4 + j_) * 4 + c_) * 64 + l];                 \
            Bq[j_ * 4 + c_] = mk4(w_.x, w_.y);                                \
          }                                                                   \
        const float b0_ = bfull[q2_ * 4 + 0], b1_ = bfull[q2_ * 4 + 1],       \
                    b2_ = bfull[q2_ * 4 + 2], b3_ = bfull[q2_ * 4 + 3];       \
        _Pragma("unroll")                                                     \
        for (int mt_ = 0; mt_ < 2; ++mt_) {                                   \
          v4f a0_ = z4, a1_ = z4, a2_ = z4, a3_ = z4;                         \
          _Pragma("unroll")                                                   \
          for (int c_ = 0; c_ < 4; ++c_) {                                    \
            a0_ = mfma16(ya16[mt_][c_], Bq[c_],      a0_);                    \
            a1_ = mfma16(ya16[mt_][c_], Bq[4 + c_],  a1_);                    \
            a2_ = mfma16(ya16[mt_][c_], Bq[8 + c_],  a2_);                    \
            a3_ = mfma16(ya16[mt_][c_], Bq[12 + c_], a3_);                    \
          }                                                                   \
          _Pragma("unroll")                                                   \
          for (int id_ = 0; id_ < 4; ++id_) {                                 \
            const float e0_ = a0_[id_] + b0_, e1_ = a1_[id_] + b1_,           \
                        e2_ = a2_[id_] + b2_, e3_ = a3_[id_] + b3_;           \
            u2 wv_;                                                           \
            wv_.x = pk_bf16(e0_, e1_);                                        \
            wv_.y = pk_bf16(e2_, e3_);                                        \
            Elds[buf_][eidx(mt_ * 16 + 4 * g + id_, x, q_)] = wv_;            \
            const float mq_ = fmaxf(fmaxf(e0_, e1_), fmaxf(e2_, e3_));        \
            mx_[mt_][id_] = fmaxf(mx_[mt_][id_], mq_);                        \
          }                                                                   \
        }                                                                     \
      }                                                                       \
      _Pragma("unroll")                                                       \
      for (int mt_ = 0; mt_ < 2; ++mt_)                                       \
        _Pragma("unroll")                                                     \
        for (int id_ = 0; id_ < 4; ++id_)                                     \
          MxT[(mt_ * 16 + 4 * g + id_) * 20 + x] = mx_[mt_][id_];             \
      {  /* same-wave transpose read: partial max over OUR 128 states */      \
        const f4* row_ = (const f4*)&MxT[(l & 31) * 20];                      \
        f4 r0_ = row_[0], r1_ = row_[1], r2_ = row_[2], r3_ = row_[3];        \
        const float m01_ = fmaxf(fmaxf(r0_.x, r0_.y), fmaxf(r0_.z, r0_.w));  \
        const float m23_ = fmaxf(fmaxf(r1_.x, r1_.y), fmaxf(r1_.z, r1_.w));  \
        const float m45_ = fmaxf(fmaxf(r2_.x, r2_.y), fmaxf(r2_.z, r2_.w));  \
        const float m67_ = fmaxf(fmaxf(r3_.x, r3_.y), fmaxf(r3_.z, r3_.w));  \
        const float Mr_ = fmaxf(fmaxf(m01_, m23_), fmaxf(m45_, m67_));        \
        if (l < 32) Mpart[buf_][wv - 1][l] = Mr_;                             \
      }                                                                       \
    }

    YLOAD(0)
    GEMMCHUNK(0)
    __syncthreads();                       // buf0 ready
#pragma unroll 1
    for (int ch = 0; ch < nch; ++ch) {
      if (ch + 1 < nch) GEMMCHUNK(ch + 1)  // overlaps consumer's scan(ch)
      __syncthreads();                     // GEMM(ch+1) done & scan(ch) done
    }
#undef GEMMCHUNK
#undef YLOAD

  } else {
    // ==================== CONSUMER WAVE ====================
    v4s pwB, pxB;
    {
      const int r0 = (4 * g) * 16 + x;
      pwB = mk4(pk_bf16(pw[r0], pw[r0 + 16]), pk_bf16(pw[r0 + 32], pw[r0 + 48]));
      pxB = mk4(pk_bf16(px[r0], px[r0 + 16]), pk_bf16(px[r0 + 32], px[r0 + 48]));
    }
    const float p0w0 = pw[4 * g + 0], p0w1 = pw[4 * g + 1],
                p0w2 = pw[4 * g + 2], p0w3 = pw[4 * g + 3];
    const float px0 = px[x];

    float acc  = 0.f;
    float msum = 0.f;
    v4f al = {0.f, 0.f, 0.f, 0.f};
    const v4f z4 = {0.f, 0.f, 0.f, 0.f};

    __syncthreads();                       // wait buf0
#pragma unroll 1
    for (int ch = 0; ch < nch; ++ch) {
      const int tb  = ch * CH;
      const int buf = ch & 1;
      const int te  = (len < tb + CH) ? len : (tb + CH);
      const u2* Eb  = Elds[buf];

      // combine the two producers' partial maxes: lane l<32 holds M[tb+l]
      float Mrow = fmaxf(Mpart[buf][0][l & 31], Mpart[buf][1][l & 31]);
      if (l < 32 && tb + l < len) msum += Mrow;

      int t = tb;
      u2 Ec = Eb[eidx(0, x, g)];

#define SCAN_STEP(TCUR, PF)                                                 \
      {                                                                     \
        u2 En_ = Ec;                                                        \
        PF                                                                  \
        const float Ms_ = rdlane(Mrow, (TCUR) & 31);                        \
        const float e0 = fexp2(bf_lo(Ec.x) - Ms_);                          \
        const float e1 = fexp2(bf_hi(Ec.x) - Ms_);                          \
        const float e2 = fexp2(bf_lo(Ec.y) - Ms_);                          \
        const float e3 = fexp2(bf_hi(Ec.y) - Ms_);                          \
        v4s a16 = mk4(pktrunc(al[0], al[1]), pktrunc(al[2], al[3]));        \
        v4f d1 = mfma16(a16, pwB, z4);                                      \
        v4s d16 = mk4(pktrunc(d1[0], d1[1]), pktrunc(d1[2], d1[3]));        \
        v4f d2 = mfma16(d16, pxB, z4);                                      \
        al[0] = d2[0] * e0; al[1] = d2[1] * e1;                             \
        al[2] = d2[2] * e2; al[3] = d2[3] * e3;                             \
        Ec = En_;                                                           \
      }

#define RENORM                                                              \
      {                                                                     \
        float S = (al[0] + al[1]) + (al[2] + al[3]);                        \
        _Pragma("unroll")                                                   \
        for (int o = 1; o <= 32; o <<= 1) S += __shfl_xor(S, o, 64);        \
        S = fmaxf(S, 1e-35f);                                               \
        const float r = __builtin_amdgcn_rcpf(S);                           \
        al[0] *= r; al[1] *= r; al[2] *= r; al[3] *= r;                     \
        acc += __log2f(S);                                                  \
      }

      if (ch == 0) {   // peel t = 0: alpha0 = prior * e
        const float Ms_ = rdlane(Mrow, 0);
        const float e0 = fexp2(bf_lo(Ec.x) - Ms_);
        const float e1 = fexp2(bf_hi(Ec.x) - Ms_);
        const float e2 = fexp2(bf_lo(Ec.y) - Ms_);
        const float e3 = fexp2(bf_hi(Ec.y) - Ms_);
        al[0] = p0w0 * px0 * e0; al[1] = p0w1 * px0 * e1;
        al[2] = p0w2 * px0 * e2; al[3] = p0w3 * px0 * e3;
        t = 1;
        if (t < te) Ec = Eb[eidx(1, x, g)];
      }

      while (t < te && (t & 7)) {     // guarded entry until 8-aligned
        SCAN_STEP(t,
          if (t + 1 < te) { En_ = Eb[eidx((t + 1) & 31, x, g)]; })
        if ((t & 7) == 7) RENORM
        ++t;
      }

      const int ng = (te - t) >> 3;   // fast path: 8-step groups
      if (ng > 0) {
        u2 E1 = Eb[eidx((t + 1) & 31, x, g)];
        float snap = 0.f, Sready = 1.0f, rdy = 1.0f;
#pragma unroll 1
        for (int gi = 0; gi < ng; ++gi) {
#pragma unroll
          for (int k = 0; k < 8; ++k) {
            u2 E2 = Eb[eidx((t + k + 2) & 31, x, g)];   // 2-deep prefetch
            const float Ms_ = rdlane(Mrow, (t + k) & 31);
            float e0 = fexp2(bf_lo(Ec.x) - Ms_);
            float e1 = fexp2(bf_hi(Ec.x) - Ms_);
            float e2 = fexp2(bf_lo(Ec.y) - Ms_);
            float e3 = fexp2(bf_hi(Ec.y) - Ms_);
            if (k == 0) {       // apply previous group's renorm (off chain)
              e0 *= rdy; e1 *= rdy; e2 *= rdy; e3 *= rdy;
              acc += __log2f(Sready);
            }
            v4s a16 = mk4(pktrunc(al[0], al[1]), pktrunc(al[2], al[3]));
            v4f d1 = mfma16(a16, pwB, z4);
            v4s d16 = mk4(pktrunc(d1[0], d1[1]), pktrunc(d1[2], d1[3]));
            v4f d2 = mfma16(d16, pxB, z4);
            al[0] = d2[0] * e0; al[1] = d2[1] * e1;
            al[2] = d2[2] * e2; al[3] = d2[3] * e3;
            if (k == 0) snap = (al[0] + al[1]) + (al[2] + al[3]);
            if (k >= 1 && k <= 6)
              snap += __shfl_xor(snap, 1 << (k - 1), 64);
            if (k == 7) {
              Sready = fmaxf(snap, 1e-35f);
              rdy = __builtin_amdgcn_rcpf(Sready);
            }
            Ec = E1; E1 = E2;
          }
          t += 8;
        }
        acc += __log2f(Sready);     // flush pending renorm
        al[0] *= rdy; al[1] *= rdy; al[2] *= rdy; al[3] *= rdy;
      }

      while (t < te) {                // guarded tail
        SCAN_STEP(t,
          if (t + 1 < te) { En_ = Eb[eidx((t + 1) & 31, x, g)]; })
        if ((t & 7) == 7) RENORM
        ++t;
      }
#undef SCAN_STEP
#undef RENORM

      __syncthreads();   // scan(ch) done; producers' GEMM(ch+1) done
    }

    // ---------- finalize ----------
    float S = (al[0] + al[1]) + (al[2] + al[3]);
#pragma unroll
    for (int o = 1; o <= 32; o <<= 1) S += __shfl_xor(S, o, 64);
    S = fmaxf(S, 1e-35f);
    acc += __log2f(S);

#pragma unroll
    for (int o = 1; o <= 32; o <<= 1) msum += __shfl_xor(msum, o, 64);

    if (l == 0) out[b] = LN2 * (acc + msum);
  }
}

} // namespace

extern "C" void kernel_launch(void* const* d_in, const int* in_sizes, int n_in,
                              void* d_out, int out_size, void* d_ws, size_t ws_size,
                              hipStream_t stream) {
  const float* seq     = (const float*)d_in[0];
  const int*   lengths = (const int*)d_in[1];
  const float* pw      = (const float*)d_in[2];
  const float* px      = (const float*)d_in[3];
  const float* py      = (const float*)d_in[4];
  float*       out     = (float*)d_out;
  u2*          wsdif   = (u2*)d_ws;    // 32 KB shared B-frag table

  hipLaunchKernelGGL(fhmm_fwd, dim3(1024), dim3(192), 0, stream,
                     seq, lengths, pw, px, py, out, wsdif);
}

// Round 20
// 95.672 us; speedup vs baseline: 1.7233x; 1.0138x over previous
//
#include <hip/hip_runtime.h>

namespace {

typedef short    v4s __attribute__((ext_vector_type(4)));
typedef float    v4f __attribute__((ext_vector_type(4)));
typedef float    f4  __attribute__((ext_vector_type(4)));
typedef unsigned u2  __attribute__((ext_vector_type(2)));

constexpr int Tt = 512;
constexpr int Dd = 64;
constexpr int CH = 32;            // chunk length (steps)
constexpr float LN2 = 0.69314718055994530942f;

__device__ __forceinline__ unsigned pk_bf16(float a, float b) {
  unsigned ua = __float_as_uint(a), ub = __float_as_uint(b);
  ua += 0x7fffu + ((ua >> 16) & 1u);
  ub += 0x7fffu + ((ub >> 16) & 1u);
  return (ua >> 16) | (ub & 0xffff0000u);
}
__device__ __forceinline__ unsigned pktrunc(float lo, float hi) {
  return __builtin_amdgcn_perm(__float_as_uint(hi), __float_as_uint(lo), 0x07060302u);
}
__device__ __forceinline__ v4s mk4(unsigned lo, unsigned hi) {
  union { unsigned u[2]; v4s s; } z;
  z.u[0] = lo; z.u[1] = hi; return z.s;
}
__device__ __forceinline__ float bf_lo(unsigned u) { return __uint_as_float(u << 16); }
__device__ __forceinline__ float bf_hi(unsigned u) { return __uint_as_float(u & 0xffff0000u); }

__device__ __forceinline__ v4f mfma16(v4s a, v4s b, v4f c) {
  return __builtin_amdgcn_mfma_f32_16x16x16bf16_1k(a, b, c, 0, 0, 0);
}
__device__ __forceinline__ float fexp2(float x) {
#if __has_builtin(__builtin_amdgcn_exp2f)
  return __builtin_amdgcn_exp2f(x);
#else
  return exp2f(x);
#endif
}
__device__ __forceinline__ float rdlane(float v, int idx) {
  return __uint_as_float(__builtin_amdgcn_readlane(__float_as_uint(v), idx));
}

// E LDS index (u2 = 8B units) for (t_local in [0,32), x, wblk)
__device__ __forceinline__ int eidx(int tl, int x, int wblk) {
  return tl * 64 + x * 4 + (wblk ^ (x >> 2));
}

__global__ __launch_bounds__(192, 3) void fhmm_fwd(
    const float* __restrict__ seq,     // [B, T, D]
    const int*   __restrict__ lengths, // [B]
    const float* __restrict__ pw,      // [16,16]
    const float* __restrict__ px,      // [16,16]
    const float* __restrict__ py,      // [16,16,64]
    float*       __restrict__ out,     // [B]
    u2*          __restrict__ wsdif)   // [16*4*64] B-frag table (shared, 32 KB)
{
  const int b   = blockIdx.x;
  const int tid = threadIdx.x;
  const int wv  = tid >> 6;   // 0 = consumer; 1 = producer-A (q0,1); 2 = producer-B (q2,3)
  const int l   = tid & 63;
  const int g   = l >> 4;
  const int x   = l & 15;

  __shared__ u2    Elds[2][CH * 64];            // double-buffered E' (2 × 16 KB)
  __shared__ float Mpart[2][2][32];             // per-chunk, per-producer max
  __shared__ __align__(16) float MxTa[CH * 20]; // producer-A private pad
  __shared__ __align__(16) float MxTb[CH * 20]; // producer-B private pad
  // LDS = 32768 + 512 + 2*2560 = 38400 -> 4 blocks/CU (12 waves/CU)

  const int len = lengths[b];
  const int nch = (len + CH - 1) >> 5;
  const float* yb = seq + (size_t)b * (Tt * Dd);

  if (wv >= 1) {
    // ==================== PRODUCER WAVE (A: q0,1 | B: q2,3) ====================
    const int qb = (wv - 1) * 2;                 // first q-tile owned
    float* MxT = (wv == 1) ? MxTa : MxTb;

    float bfull[8];                              // bases for OUR 8 states only
#pragma unroll
    for (int s8 = 0; s8 < 8; ++s8) {
      const int st = qb * 4 + s8;
      float pt = 0.f;
#pragma unroll
      for (int c = 0; c < 4; ++c) {
        f4 pv = *(const f4*)(py + (st * 16 + x) * 64 + c * 16 + g * 4);
        float q0 = __log2f(1.f - pv.x), q1 = __log2f(1.f - pv.y),
              q2 = __log2f(1.f - pv.z), q3 = __log2f(1.f - pv.w);
        pt += (q0 + q1) + (q2 + q3);
        u2 wvv;
        wvv.x = pk_bf16(__log2f(pv.x) - q0, __log2f(pv.y) - q1);
        wvv.y = pk_bf16(__log2f(pv.z) - q2, __log2f(pv.w) - q3);
        wsdif[(st * 4 + c) * 64 + l] = wvv;      // all blocks: identical bytes
      }
      pt += __shfl_xor(pt, 16, 64);
      pt += __shfl_xor(pt, 32, 64);
      bfull[s8] = pt;                            // base[st*16 + x]
    }

    const v4f z4 = {0.f, 0.f, 0.f, 0.f};
    f4 yv[8];                                    // next-chunk raw y (32 VGPR)

#define YLOAD(TB)                                                             \
    _Pragma("unroll")                                                         \
    for (int m_ = 0; m_ < 2; ++m_)                                            \
      _Pragma("unroll")                                                       \
      for (int c_ = 0; c_ < 4; ++c_)                                          \
        yv[m_ * 4 + c_] = *(const f4*)(yb +                                   \
            (size_t)((TB) + m_ * 16 + x) * 64 + c_ * 16 + g * 4);

#define GEMMCHUNK(CHIDX)                                                      \
    {                                                                         \
      const int buf_ = (CHIDX) & 1;                                           \
      v4s ya16[2][4];                                                         \
      _Pragma("unroll")                                                       \
      for (int i_ = 0; i_ < 8; ++i_)                                          \
        ya16[i_ >> 2][i_ & 3] = mk4(pktrunc(yv[i_].x, yv[i_].y),              \
                                    pktrunc(yv[i_].z, yv[i_].w));             \
      if ((CHIDX) + 1 < nch) { YLOAD(((CHIDX) + 1) * CH) }                    \
      float mx_[2][4];                                                        \
      _Pragma("unroll")                                                       \
      for (int mt_ = 0; mt_ < 2; ++mt_)                                       \
        _Pragma("unroll")                                                     \
        for (int id_ = 0; id_ < 4; ++id_) mx_[mt_][id_] = -1e30f;             \
      _Pragma("unroll")                                                       \
      for (int q2_ = 0; q2_ < 2; ++q2_) {                                     \
        const int q_ = qb + q2_;                                              \
        v4s Bq[16];                                                           \
        _Pragma("unroll")                                                     \
        for (int j_ = 0; j_ < 4; ++j_)                                        \
          _Pragma("unroll")                                                   \
          for (int c_ = 0; c_ < 4; ++c_) {                                    \
            u2 w_ = wsdif[((q_ * 4 + j_) * 4 + c_) * 64 + l];                 \
            Bq[j_ * 4 + c_] = mk4(w_.x, w_.y);                                \
          }                                                                   \
        const float b0_ = bfull[q2_ * 4 + 0], b1_ = bfull[q2_ * 4 + 1],       \
                    b2_ = bfull[q2_ * 4 + 2], b3_ = bfull[q2_ * 4 + 3];       \
        _Pragma("unroll")                                                     \
        for (int mt_ = 0; mt_ < 2; ++mt_) {                                   \
          v4f a0_ = z4, a1_ = z4, a2_ = z4, a3_ = z4;                         \
          _Pragma("unroll")                                                   \
          for (int c_ = 0; c_ < 4; ++c_) {                                    \
            a0_ = mfma16(ya16[mt_][c_], Bq[c_],      a0_);                    \
            a1_ = mfma16(ya16[mt_][c_], Bq[4 + c_],  a1_);                    \
            a2_ = mfma16(ya16[mt_][c_], Bq[8 + c_],  a2_);                    \
            a3_ = mfma16(ya16[mt_][c_], Bq[12 + c_], a3_);                    \
          }                                                                   \
          _Pragma("unroll")                                                   \
          for (int id_ = 0; id_ < 4; ++id_) {                                 \
            const float e0_ = a0_[id_] + b0_, e1_ = a1_[id_] + b1_,           \
                        e2_ = a2_[id_] + b2_, e3_ = a3_[id_] + b3_;           \
            u2 wv_;                                                           \
            wv_.x = pk_bf16(e0_, e1_);                                        \
            wv_.y = pk_bf16(e2_, e3_);                                        \
            Elds[buf_][eidx(mt_ * 16 + 4 * g + id_, x, q_)] = wv_;            \
            const float mq_ = fmaxf(fmaxf(e0_, e1_), fmaxf(e2_, e3_));        \
            mx_[mt_][id_] = fmaxf(mx_[mt_][id_], mq_);                        \
          }                                                                   \
        }                                                                     \
      }                                                                       \
      _Pragma("unroll")                                                       \
      for (int mt_ = 0; mt_ < 2; ++mt_)                                       \
        _Pragma("unroll")                                                     \
        for (int id_ = 0; id_ < 4; ++id_)                                     \
          MxT[(mt_ * 16 + 4 * g + id_) * 20 + x] = mx_[mt_][id_];             \
      {  /* same-wave transpose read: partial max over OUR 128 states */      \
        const f4* row_ = (const f4*)&MxT[(l & 31) * 20];                      \
        f4 r0_ = row_[0], r1_ = row_[1], r2_ = row_[2], r3_ = row_[3];        \
        const float m01_ = fmaxf(fmaxf(r0_.x, r0_.y), fmaxf(r0_.z, r0_.w));  \
        const float m23_ = fmaxf(fmaxf(r1_.x, r1_.y), fmaxf(r1_.z, r1_.w));  \
        const float m45_ = fmaxf(fmaxf(r2_.x, r2_.y), fmaxf(r2_.z, r2_.w));  \
        const float m67_ = fmaxf(fmaxf(r3_.x, r3_.y), fmaxf(r3_.z, r3_.w));  \
        const float Mr_ = fmaxf(fmaxf(m01_, m23_), fmaxf(m45_, m67_));        \
        if (l < 32) Mpart[buf_][wv - 1][l] = Mr_;                             \
      }                                                                       \
    }

    YLOAD(0)
    GEMMCHUNK(0)
    __syncthreads();                       // buf0 ready
#pragma unroll 1
    for (int ch = 0; ch < nch; ++ch) {
      if (ch + 1 < nch) GEMMCHUNK(ch + 1)  // overlaps consumer's scan(ch)
      __syncthreads();                     // GEMM(ch+1) done & scan(ch) done
    }
#undef GEMMCHUNK
#undef YLOAD

  } else {
    // ==================== CONSUMER WAVE ====================
    __builtin_amdgcn_s_setprio(1);         // consumer = the critical path
    v4s pwB, pxB;
    {
      const int r0 = (4 * g) * 16 + x;
      pwB = mk4(pk_bf16(pw[r0], pw[r0 + 16]), pk_bf16(pw[r0 + 32], pw[r0 + 48]));
      pxB = mk4(pk_bf16(px[r0], px[r0 + 16]), pk_bf16(px[r0 + 32], px[r0 + 48]));
    }
    const v4s onesB = mk4(0x3f803f80u, 0x3f803f80u);  // bf16 1.0 B-frag
    const float p0w0 = pw[4 * g + 0], p0w1 = pw[4 * g + 1],
                p0w2 = pw[4 * g + 2], p0w3 = pw[4 * g + 3];
    const float px0 = px[x];

    float acc  = 0.f;
    float msum = 0.f;
    v4f al = {0.f, 0.f, 0.f, 0.f};
    const v4f z4 = {0.f, 0.f, 0.f, 0.f};

    __syncthreads();                       // wait buf0
#pragma unroll 1
    for (int ch = 0; ch < nch; ++ch) {
      const int tb  = ch * CH;
      const int buf = ch & 1;
      const int te  = (len < tb + CH) ? len : (tb + CH);
      const u2* Eb  = Elds[buf];

      // combine the two producers' partial maxes: lane l<32 holds M[tb+l]
      float Mrow = fmaxf(Mpart[buf][0][l & 31], Mpart[buf][1][l & 31]);
      if (l < 32 && tb + l < len) msum += Mrow;

      int t = tb;
      u2 Ec = Eb[eidx(0, x, g)];

#define SCAN_STEP(TCUR, PF)                                                 \
      {                                                                     \
        u2 En_ = Ec;                                                        \
        PF                                                                  \
        const float Ms_ = rdlane(Mrow, (TCUR) & 31);                        \
        const float e0 = fexp2(bf_lo(Ec.x) - Ms_);                          \
        const float e1 = fexp2(bf_hi(Ec.x) - Ms_);                          \
        const float e2 = fexp2(bf_lo(Ec.y) - Ms_);                          \
        const float e3 = fexp2(bf_hi(Ec.y) - Ms_);                          \
        v4s a16 = mk4(pktrunc(al[0], al[1]), pktrunc(al[2], al[3]));        \
        v4f d1 = mfma16(a16, pwB, z4);                                      \
        v4s d16 = mk4(pktrunc(d1[0], d1[1]), pktrunc(d1[2], d1[3]));        \
        v4f d2 = mfma16(d16, pxB, z4);                                      \
        al[0] = d2[0] * e0; al[1] = d2[1] * e1;                             \
        al[2] = d2[2] * e2; al[3] = d2[3] * e3;                             \
        Ec = En_;                                                           \
      }

#define RENORM                                                              \
      {                                                                     \
        float S = (al[0] + al[1]) + (al[2] + al[3]);                        \
        _Pragma("unroll")                                                   \
        for (int o = 1; o <= 32; o <<= 1) S += __shfl_xor(S, o, 64);        \
        S = fmaxf(S, 1e-35f);                                               \
        const float r = __builtin_amdgcn_rcpf(S);                           \
        al[0] *= r; al[1] *= r; al[2] *= r; al[3] *= r;                     \
        acc += __log2f(S);                                                  \
      }

      if (ch == 0) {   // peel t = 0: alpha0 = prior * e
        const float Ms_ = rdlane(Mrow, 0);
        const float e0 = fexp2(bf_lo(Ec.x) - Ms_);
        const float e1 = fexp2(bf_hi(Ec.x) - Ms_);
        const float e2 = fexp2(bf_lo(Ec.y) - Ms_);
        const float e3 = fexp2(bf_hi(Ec.y) - Ms_);
        al[0] = p0w0 * px0 * e0; al[1] = p0w1 * px0 * e1;
        al[2] = p0w2 * px0 * e2; al[3] = p0w3 * px0 * e3;
        t = 1;
        if (t < te) Ec = Eb[eidx(1, x, g)];
      }

      while (t < te && (t & 7)) {     // guarded entry until 8-aligned
        SCAN_STEP(t,
          if (t + 1 < te) { En_ = Eb[eidx((t + 1) & 31, x, g)]; })
        if ((t & 7) == 7) RENORM
        ++t;
      }

      // fast path: 8-step groups, 3-deep E prefetch, MFMA-pipelined renorm
      // (keeps the lgkmcnt queue free of cross-lane ops: E loads only)
      const int ng = (te - t) >> 3;
      if (ng > 0) {
        u2 E1 = Eb[eidx((t + 1) & 31, x, g)];
        u2 E2 = Eb[eidx((t + 2) & 31, x, g)];
        float Sready = 1.0f, rdy = 1.0f;
        v4f sm1 = z4, sm2 = z4;
        v4s sb = onesB;
#pragma unroll 1
        for (int gi = 0; gi < ng; ++gi) {
#pragma unroll
          for (int k = 0; k < 8; ++k) {
            u2 E3 = Eb[eidx((t + k + 3) & 31, x, g)];   // 3-deep prefetch
            const float Ms_ = rdlane(Mrow, (t + k) & 31);
            float e0 = fexp2(bf_lo(Ec.x) - Ms_);
            float e1 = fexp2(bf_hi(Ec.x) - Ms_);
            float e2 = fexp2(bf_lo(Ec.y) - Ms_);
            float e3 = fexp2(bf_hi(Ec.y) - Ms_);
            if (k == 0) {       // apply previous group's renorm (off chain)
              e0 *= rdy; e1 *= rdy; e2 *= rdy; e3 *= rdy;
              acc += __log2f(Sready);
            }
            v4s a16 = mk4(pktrunc(al[0], al[1]), pktrunc(al[2], al[3]));
            if (k == 1) sm1 = mfma16(a16, onesB, z4);   // S stage 1: col-sums
            v4f d1 = mfma16(a16, pwB, z4);
            if (k == 2) sb = mk4(pktrunc(sm1[0], sm1[1]),
                                 pktrunc(sm1[2], sm1[3]));
            v4s d16 = mk4(pktrunc(d1[0], d1[1]), pktrunc(d1[2], d1[3]));
            if (k == 3) sm2 = mfma16(sb, onesB, z4);    // S stage 2: total
            v4f d2 = mfma16(d16, pxB, z4);
            if (k == 4) {        // S broadcast ready in every lane/reg
              Sready = fmaxf(sm2[0], 1e-35f);
              rdy = __builtin_amdgcn_rcpf(Sready);
            }
            al[0] = d2[0] * e0; al[1] = d2[1] * e1;
            al[2] = d2[2] * e2; al[3] = d2[3] * e3;
            Ec = E1; E1 = E2; E2 = E3;
          }
          t += 8;
        }
        acc += __log2f(Sready);     // flush pending renorm
        al[0] *= rdy; al[1] *= rdy; al[2] *= rdy; al[3] *= rdy;
      }

      while (t < te) {                // guarded tail
        SCAN_STEP(t,
          if (t + 1 < te) { En_ = Eb[eidx((t + 1) & 31, x, g)]; })
        if ((t & 7) == 7) RENORM
        ++t;
      }
#undef SCAN_STEP
#undef RENORM

      __syncthreads();   // scan(ch) done; producers' GEMM(ch+1) done
    }

    // ---------- finalize ----------
    float S = (al[0] + al[1]) + (al[2] + al[3]);
#pragma unroll
    for (int o = 1; o <= 32; o <<= 1) S += __shfl_xor(S, o, 64);
    S = fmaxf(S, 1e-35f);
    acc += __log2f(S);

#pragma unroll
    for (int o = 1; o <= 32; o <<= 1) msum += __shfl_xor(msum, o, 64);

    if (l == 0) out[b] = LN2 * (acc + msum);
  }
}

} // namespace

extern "C" void kernel_launch(void* const* d_in, const int* in_sizes, int n_in,
                              void* d_out, int out_size, void* d_ws, size_t ws_size,
                              hipStream_t stream) {
  const float* seq     = (const float*)d_in[0];
  const int*   lengths = (const int*)d_in[1];
  const float* pw      = (const float*)d_in[2];
  const float* px      = (const float*)d_in[3];
  const float* py      = (const float*)d_in[4];
  float*       out     = (float*)d_out;
  u2*          wsdif   = (u2*)d_ws;    // 32 KB shared B-frag table

  hipLaunchKernelGGL(fhmm_fwd, dim3(1024), dim3(192), 0, stream,
                     seq, lengths, pw, px, py, out, wsdif);
}